// Round 1
// baseline (1758.121 us; speedup 1.0000x reference)
//
#include <hip/hip_runtime.h>
#include <cstdint>
#include <cstddef>

typedef _Float16 half_t;
typedef __attribute__((ext_vector_type(4))) _Float16 half4;
typedef __attribute__((ext_vector_type(8))) _Float16 half8;
typedef __attribute__((ext_vector_type(4))) float f32x4;
typedef __attribute__((ext_vector_type(8))) float f32x8;

#define DM 1024
#define NHEAD 16
#define DHEAD 64
#define BATCH 4
#define SEQ 2048
#define MROWS (BATCH*SEQ)   // 8192

// ---------------------------------------------------------------------------
// Kernel 1: fp32 -> fp16 convert of q,k,v (layout unchanged, [B*S, 1024])
// ---------------------------------------------------------------------------
__global__ __launch_bounds__(256) void cvt_kernel(
    const float* __restrict__ q, const float* __restrict__ k, const float* __restrict__ v,
    half_t* __restrict__ q16, half_t* __restrict__ k16, half_t* __restrict__ v16) {
  const float* src = blockIdx.y == 0 ? q : (blockIdx.y == 1 ? k : v);
  half_t* dst = blockIdx.y == 0 ? q16 : (blockIdx.y == 1 ? k16 : v16);
  size_t e = ((size_t)blockIdx.x * 256 + threadIdx.x) * 8;
  f32x8 a = *(const f32x8*)&src[e];
  *(half8*)&dst[e] = __builtin_convertvector(a, half8);
}

// ---------------------------------------------------------------------------
// Kernel 2: W [K=1024][N=1024] fp32 -> Wt [N][K] fp16 (B^T layout for bt-GEMM)
// 64x64 tiles through LDS (pad 65 to break bank conflicts)
// ---------------------------------------------------------------------------
__global__ __launch_bounds__(256) void wt_kernel(
    const float* __restrict__ Wq, const float* __restrict__ Wk,
    const float* __restrict__ Wv, const float* __restrict__ Wo,
    half_t* __restrict__ Tq, half_t* __restrict__ Tk,
    half_t* __restrict__ Tv, half_t* __restrict__ To) {
  __shared__ float tile[64][65];
  const float* W = blockIdx.z == 0 ? Wq : blockIdx.z == 1 ? Wk : blockIdx.z == 2 ? Wv : Wo;
  half_t* T = blockIdx.z == 0 ? Tq : blockIdx.z == 1 ? Tk : blockIdx.z == 2 ? Tv : To;
  int t = threadIdx.x;
  int k0 = blockIdx.x * 64, n0 = blockIdx.y * 64;
  int rr = t >> 4, cc = (t & 15) * 4;
#pragma unroll
  for (int i = 0; i < 4; i++) {
    f32x4 val = *(const f32x4*)&W[(size_t)(k0 + i * 16 + rr) * DM + n0 + cc];
    tile[i * 16 + rr][cc + 0] = val[0];
    tile[i * 16 + rr][cc + 1] = val[1];
    tile[i * 16 + rr][cc + 2] = val[2];
    tile[i * 16 + rr][cc + 3] = val[3];
  }
  __syncthreads();
#pragma unroll
  for (int i = 0; i < 4; i++) {
    int nrow = i * 16 + rr;
    f32x4 val;
    val[0] = tile[cc + 0][nrow];
    val[1] = tile[cc + 1][nrow];
    val[2] = tile[cc + 2][nrow];
    val[3] = tile[cc + 3][nrow];
    *(half4*)&T[(size_t)(n0 + nrow) * DM + k0 + cc] = __builtin_convertvector(val, half4);
  }
}

// ---------------------------------------------------------------------------
// Kernel 3: bt-GEMM  C[M=8192,N=1024] = A[M,K=1024] @ Bt[N,K]^T  (f16 MFMA)
// 128x128 block tile, 4 waves (2x2), each 64x64 = 4x4 MFMA tiles, BK=32.
// LDS rows padded to 40 halfs (80B = odd multiple of 16B -> conflict-light
// ds_read_b128, still 16B aligned).
// mode 0: Qh [b,h,s,d] fp16, (acc+bias)*0.125
// mode 1: Kh [b,h,s,d] fp16
// mode 2: Vt [b,h,d,s] fp16 (transposed for PV B-operand)
// mode 3: out [m,n] fp32 (+bias)
// ---------------------------------------------------------------------------
#define LDT 40

__global__ __launch_bounds__(256) void gemm_bt(
    const half_t* __restrict__ A, const half_t* __restrict__ Bt,
    const float* __restrict__ bias, void* __restrict__ out, int mode) {
  __shared__ half_t As[128 * LDT];
  __shared__ half_t Bs[128 * LDT];
  int t = threadIdx.x, lane = t & 63, w = t >> 6;
  int wm = w >> 1, wn = w & 1;
  int m0 = blockIdx.y * 128, n0 = blockIdx.x * 128;
  int col = lane & 15, q4 = (lane >> 4) * 4, koff = (lane >> 4) * 8;
  int sr = t >> 2, sc = (t & 3) * 8;
  f32x4 acc[4][4] = {};

  for (int k0 = 0; k0 < DM; k0 += 32) {
    __syncthreads();
    *(half8*)&As[sr * LDT + sc]        = *(const half8*)&A[(size_t)(m0 + sr) * DM + k0 + sc];
    *(half8*)&As[(64 + sr) * LDT + sc] = *(const half8*)&A[(size_t)(m0 + 64 + sr) * DM + k0 + sc];
    *(half8*)&Bs[sr * LDT + sc]        = *(const half8*)&Bt[(size_t)(n0 + sr) * DM + k0 + sc];
    *(half8*)&Bs[(64 + sr) * LDT + sc] = *(const half8*)&Bt[(size_t)(n0 + 64 + sr) * DM + k0 + sc];
    __syncthreads();
    half8 af[4], bf[4];
#pragma unroll
    for (int i = 0; i < 4; i++)
      af[i] = *(const half8*)&As[(wm * 64 + i * 16 + col) * LDT + koff];
#pragma unroll
    for (int j = 0; j < 4; j++)
      bf[j] = *(const half8*)&Bs[(wn * 64 + j * 16 + col) * LDT + koff];
#pragma unroll
    for (int i = 0; i < 4; i++)
#pragma unroll
      for (int j = 0; j < 4; j++)
        acc[i][j] = __builtin_amdgcn_mfma_f32_16x16x32_f16(af[i], bf[j], acc[i][j], 0, 0, 0);
  }

  // epilogue. C/D layout: col = lane&15, row = (lane>>4)*4 + reg (m89-verified)
  if (mode == 3) {
    float* O = (float*)out;
#pragma unroll
    for (int i = 0; i < 4; i++)
#pragma unroll
      for (int j = 0; j < 4; j++) {
        int m = m0 + wm * 64 + i * 16 + q4;
        int n = n0 + wn * 64 + j * 16 + col;
        float bv = bias[n];
#pragma unroll
        for (int r = 0; r < 4; r++)
          O[(size_t)(m + r) * DM + n] = acc[i][j][r] + bv;
      }
  } else if (mode == 2) {
    half_t* V = (half_t*)out;
#pragma unroll
    for (int i = 0; i < 4; i++)
#pragma unroll
      for (int j = 0; j < 4; j++) {
        int m = m0 + wm * 64 + i * 16 + q4;
        int n = n0 + wn * 64 + j * 16 + col;
        float bv = bias[n];
        int b = m >> 11, s = m & 2047;
        int h = n >> 6, d = n & 63;
        f32x4 vv;
#pragma unroll
        for (int r = 0; r < 4; r++) vv[r] = acc[i][j][r] + bv;
        *(half4*)&V[((size_t)(b * NHEAD + h) * DHEAD + d) * SEQ + s] = __builtin_convertvector(vv, half4);
      }
  } else {
    half_t* Y = (half_t*)out;
    float sc2 = (mode == 0) ? 0.125f : 1.0f;  // qh / sqrt(64) folded here
#pragma unroll
    for (int i = 0; i < 4; i++)
#pragma unroll
      for (int j = 0; j < 4; j++) {
        int m = m0 + wm * 64 + i * 16 + q4;
        int n = n0 + wn * 64 + j * 16 + col;
        float bv = bias[n];
        int b = m >> 11, s = m & 2047;
        int h = n >> 6, d = n & 63;
#pragma unroll
        for (int r = 0; r < 4; r++)
          Y[((size_t)(b * NHEAD + h) * SEQ + (s + r)) * DHEAD + d] = (half_t)((acc[i][j][r] + bv) * sc2);
      }
  }
}

// ---------------------------------------------------------------------------
// Kernel 4: attention per (b,h, 64-row q tile). Two-pass flash:
//  pass A: running row max m, sumexp l over 16 K-tiles of 128
//  pass B: recompute S, p = exp(s-m)/l, write fp32 attn to d_out,
//          P -> LDS (A-operand layout), PV MFMA, write fp16 ctx [b,s,h*64+d]
// LDS row strides padded to odd multiples of 16B.
// ---------------------------------------------------------------------------
#define LQ 72    // 64 + 8, 144B rows
#define LV 136   // 128 + 8, 272B rows

__global__ __launch_bounds__(256) void attn_kernel(
    const half_t* __restrict__ Qh, const half_t* __restrict__ Kh,
    const half_t* __restrict__ Vt, float* __restrict__ attn,
    half_t* __restrict__ ctx) {
  __shared__ half_t Qs[64 * LQ];
  __shared__ half_t Ks[128 * LQ];
  __shared__ half_t Vs[64 * LV];
  __shared__ half_t Ps[64 * LV];
  __shared__ float sm_m[64], sm_l[64], red[2][64];

  int t = threadIdx.x, lane = t & 63, w = t >> 6;
  int wm = w >> 1, wn = w & 1;
  int col = lane & 15, quad = lane >> 4, q4 = quad * 4, koff = quad * 8;
  int bh = blockIdx.y;
  int q0 = blockIdx.x * 64;
  const half_t* Qg = Qh + ((size_t)bh * SEQ + q0) * DHEAD;
  const half_t* Kg = Kh + (size_t)bh * SEQ * DHEAD;
  const half_t* Vg = Vt + (size_t)bh * DHEAD * SEQ;

  // load Q tile (64x64) once
#pragma unroll
  for (int i = 0; i < 2; i++) {
    int e = i * 2048 + t * 8;
    *(half8*)&Qs[(e >> 6) * LQ + (e & 63)] = *(const half8*)&Qg[e];
  }
  if (t < 64) { sm_m[t] = -3.0e38f; sm_l[t] = 0.f; }

  // ---- pass A: stats ----
  for (int kt = 0; kt < 16; kt++) {
    __syncthreads();
#pragma unroll
    for (int i = 0; i < 4; i++) {
      int e = i * 2048 + t * 8;
      *(half8*)&Ks[(e >> 6) * LQ + (e & 63)] = *(const half8*)&Kg[(size_t)kt * 128 * DHEAD + e];
    }
    __syncthreads();
    f32x4 sacc[2][4] = {};
#pragma unroll
    for (int ks = 0; ks < 64; ks += 32) {
      half8 af[2], bf[4];
#pragma unroll
      for (int i = 0; i < 2; i++)
        af[i] = *(const half8*)&Qs[(wm * 32 + i * 16 + col) * LQ + ks + koff];
#pragma unroll
      for (int j = 0; j < 4; j++)
        bf[j] = *(const half8*)&Ks[(wn * 64 + j * 16 + col) * LQ + ks + koff];
#pragma unroll
      for (int i = 0; i < 2; i++)
#pragma unroll
        for (int j = 0; j < 4; j++)
          sacc[i][j] = __builtin_amdgcn_mfma_f32_16x16x32_f16(af[i], bf[j], sacc[i][j], 0, 0, 0);
    }
    // row max of this tile
#pragma unroll
    for (int i = 0; i < 2; i++)
#pragma unroll
      for (int r = 0; r < 4; r++) {
        float v = fmaxf(fmaxf(sacc[i][0][r], sacc[i][1][r]), fmaxf(sacc[i][2][r], sacc[i][3][r]));
        v = fmaxf(v, __shfl_xor(v, 1));
        v = fmaxf(v, __shfl_xor(v, 2));
        v = fmaxf(v, __shfl_xor(v, 4));
        v = fmaxf(v, __shfl_xor(v, 8));
        if (col == 0) red[wn][wm * 32 + i * 16 + q4 + r] = v;
      }
    __syncthreads();
    if (t < 64) {
      float tm = fmaxf(red[0][t], red[1][t]);
      float nm = fmaxf(sm_m[t], tm);
      sm_l[t] *= __expf(sm_m[t] - nm);
      sm_m[t] = nm;
    }
    __syncthreads();
    // row sumexp of this tile vs new max
#pragma unroll
    for (int i = 0; i < 2; i++)
#pragma unroll
      for (int r = 0; r < 4; r++) {
        int row = wm * 32 + i * 16 + q4 + r;
        float nm = sm_m[row];
        float s = __expf(sacc[i][0][r] - nm) + __expf(sacc[i][1][r] - nm) +
                  __expf(sacc[i][2][r] - nm) + __expf(sacc[i][3][r] - nm);
        s += __shfl_xor(s, 1);
        s += __shfl_xor(s, 2);
        s += __shfl_xor(s, 4);
        s += __shfl_xor(s, 8);
        if (col == 0) red[wn][row] = s;
      }
    __syncthreads();
    if (t < 64) sm_l[t] += red[0][t] + red[1][t];
  }
  __syncthreads();
  if (t < 64) sm_l[t] = 1.0f / sm_l[t];  // invert once

  // ---- pass B: p, attn write, PV ----
  f32x4 oacc[4] = {};
  for (int kt = 0; kt < 16; kt++) {
    __syncthreads();
#pragma unroll
    for (int i = 0; i < 4; i++) {
      int e = i * 2048 + t * 8;
      *(half8*)&Ks[(e >> 6) * LQ + (e & 63)] = *(const half8*)&Kg[(size_t)kt * 128 * DHEAD + e];
    }
#pragma unroll
    for (int i = 0; i < 4; i++) {
      int e = i * 2048 + t * 8;
      int r = e >> 7, c = e & 127;
      *(half8*)&Vs[r * LV + c] = *(const half8*)&Vg[(size_t)r * SEQ + kt * 128 + c];
    }
    __syncthreads();
    f32x4 sacc[2][4] = {};
#pragma unroll
    for (int ks = 0; ks < 64; ks += 32) {
      half8 af[2], bf[4];
#pragma unroll
      for (int i = 0; i < 2; i++)
        af[i] = *(const half8*)&Qs[(wm * 32 + i * 16 + col) * LQ + ks + koff];
#pragma unroll
      for (int j = 0; j < 4; j++)
        bf[j] = *(const half8*)&Ks[(wn * 64 + j * 16 + col) * LQ + ks + koff];
#pragma unroll
      for (int i = 0; i < 2; i++)
#pragma unroll
        for (int j = 0; j < 4; j++)
          sacc[i][j] = __builtin_amdgcn_mfma_f32_16x16x32_f16(af[i], bf[j], sacc[i][j], 0, 0, 0);
    }
    // exact softmax probs: write fp32 attn + fp16 Ps
#pragma unroll
    for (int i = 0; i < 2; i++)
#pragma unroll
      for (int j = 0; j < 4; j++) {
        int row = wm * 32 + i * 16 + q4;
        int kk = wn * 64 + j * 16 + col;
#pragma unroll
        for (int r = 0; r < 4; r++) {
          float p = __expf(sacc[i][j][r] - sm_m[row + r]) * sm_l[row + r];
          attn[((size_t)(bh * SEQ + q0 + row + r)) * SEQ + kt * 128 + kk] = p;
          Ps[(row + r) * LV + kk] = (half_t)p;
        }
      }
    __syncthreads();
    // PV: wave w handles O rows w*16..w*16+15, all 64 d cols
#pragma unroll
    for (int ks = 0; ks < 4; ks++) {
      half8 pa = *(const half8*)&Ps[(w * 16 + col) * LV + ks * 32 + koff];
#pragma unroll
      for (int j = 0; j < 4; j++) {
        half8 vb = *(const half8*)&Vs[(j * 16 + col) * LV + ks * 32 + koff];
        oacc[j] = __builtin_amdgcn_mfma_f32_16x16x32_f16(pa, vb, oacc[j], 0, 0, 0);
      }
    }
  }
  // ctx epilogue: [b][s][h*64+d] fp16
  int b = bh >> 4, h = bh & 15;
#pragma unroll
  for (int j = 0; j < 4; j++)
#pragma unroll
    for (int r = 0; r < 4; r++) {
      int qrow = w * 16 + q4 + r;
      ctx[((size_t)(b * SEQ + q0 + qrow)) * DM + h * DHEAD + j * 16 + col] = (half_t)oacc[j][r];
    }
}

// ---------------------------------------------------------------------------
// launcher
// ---------------------------------------------------------------------------
extern "C" void kernel_launch(void* const* d_in, const int* in_sizes, int n_in,
                              void* d_out, int out_size, void* d_ws, size_t ws_size,
                              hipStream_t stream) {
  const float* q  = (const float*)d_in[0];
  const float* k  = (const float*)d_in[1];
  const float* v  = (const float*)d_in[2];
  const float* Wq = (const float*)d_in[3];
  const float* bq = (const float*)d_in[4];
  const float* Wk = (const float*)d_in[5];
  const float* bk = (const float*)d_in[6];
  const float* Wv = (const float*)d_in[7];
  const float* bv = (const float*)d_in[8];
  const float* Wo = (const float*)d_in[9];
  const float* bo = (const float*)d_in[10];

  char* ws = (char*)d_ws;
  const size_t MB = 1024 * 1024;
  half_t* Wtq = (half_t*)(ws + 0 * MB);
  half_t* Wtk = (half_t*)(ws + 2 * MB);
  half_t* Wtv = (half_t*)(ws + 4 * MB);
  half_t* Wto = (half_t*)(ws + 6 * MB);
  half_t* q16 = (half_t*)(ws + 8 * MB);
  half_t* k16 = (half_t*)(ws + 24 * MB);
  half_t* v16 = (half_t*)(ws + 40 * MB);
  half_t* Qh  = (half_t*)(ws + 56 * MB);
  half_t* Kh  = (half_t*)(ws + 72 * MB);
  half_t* Vt  = (half_t*)(ws + 88 * MB);
  half_t* ctx = (half_t*)(ws + 104 * MB);  // 120 MB total

  float* out_f = (float*)d_out;
  float* attn  = out_f + (size_t)MROWS * DM;  // attn after out, 268M floats

  cvt_kernel<<<dim3(4096, 3), 256, 0, stream>>>(q, k, v, q16, k16, v16);
  wt_kernel<<<dim3(16, 16, 4), 256, 0, stream>>>(Wq, Wk, Wv, Wo, Wtq, Wtk, Wtv, Wto);
  gemm_bt<<<dim3(8, 64), 256, 0, stream>>>(q16, Wtq, bq, (void*)Qh, 0);
  gemm_bt<<<dim3(8, 64), 256, 0, stream>>>(k16, Wtk, bk, (void*)Kh, 1);
  gemm_bt<<<dim3(8, 64), 256, 0, stream>>>(v16, Wtv, bv, (void*)Vt, 2);
  attn_kernel<<<dim3(32, 64), 256, 0, stream>>>(Qh, Kh, Vt, attn, ctx);
  gemm_bt<<<dim3(8, 64), 256, 0, stream>>>(ctx, Wto, bo, (void*)d_out, 3);
}